// Round 2
// 109.938 us; speedup vs baseline: 1.0132x; 1.0132x over previous
//
#include <hip/hip_runtime.h>
#include <math.h>

constexpr int NBINS = 1025;              // 2048/2 + 1
constexpr int NROWS = 128 * 192;         // B * P
constexpr int RPB   = 16;                // rows per block (4 per wave)
constexpr int NBLK  = NROWS / RPB;       // 1536 blocks = 6/CU, fully resident

// R8: single-instruction bf16 pack. v_cvt_pk_bf16_f32 is RNE and packs
// lo=src0, hi=src1 -- identical bits to the old manual f2bf path
// (u + 0x7FFF + ((u>>16)&1)) >> 16, but 1 VALU op instead of ~10.
// Output layout (empirical, R3/R4): LOW half = im, HIGH half = re.
__device__ inline unsigned int pack_bf16(float im, float re) {
    unsigned int u;
    asm("v_cvt_pk_bf16_f32 %0, %1, %2" : "=v"(u) : "v"(im), "v"(re));
    return u;
}

// H(theta) = (d + i*g1*s)/(d + i*g2*s), theta = pi*k/1024, h = theta/2.
// Product form (cancellation-safe near resonance):
//   dp = (sh - st)(sh + st),  sh = sin(w0/2), st = sin(h); d = 2*dp
//   s  = sin(theta) = 2*sin(h)*cos(h)   [tab stores (st, s)]
//   re = (dp^2 + (a^2/4) s^2) / (dp^2 + (g2^2/4) s^2)
//   im = ((g1-g2)/2)*s*dp     / (dp^2 + (g2^2/4) s^2)
// Row consts P = (sh, alpha^2/4, g2^2/4, (g1-g2)/2).
//
// Store-width trick (R7): rows are 1025 dwords, so row base byte = 4100*row
// is 8B-aligned iff row even; base+4 is 8B-aligned iff row odd. Pair bins
// (k,k+1) from koff=row&1 -> 512 aligned dwordx2 stores covering 1024 bins;
// the leftover bin (k=1024 even rows / k=0 odd rows) is exactly H=1
// (num==den at theta=0 and pi) -> constant 0x3F800000.
__global__ __launch_bounds__(256) void eq_kernel(
    const float* __restrict__ center,
    const float* __restrict__ gain,
    const float* __restrict__ q,
    unsigned int* __restrict__ out)
{
    __shared__ float2 tab[NBINS];        // (sin h, sin theta), k = 0..1024
    __shared__ float4 rp[RPB];           // (sh, A2, G2, GD) per row

    const int tid  = threadIdx.x;
    const int wave = tid >> 6;
    const int lane = tid & 63;

    if (tid < RPB) {
        const int row = blockIdx.x * RPB + tid;
        float w0 = 1.4247585730565955e-4f * center[row];   // 2*pi/44100
        float sh, ch;
        sincosf(0.5f * w0, &sh, &ch);                      // sin/cos of w0/2
        float A = exp2f(0.08304820237218406f * gain[row]); // 10^(gain/40)
        float alpha = sh * ch / q[row];                    // sin(w0)/(2q)
        float g2 = alpha / A;
        float gd = alpha * A - g2;                         // g1 - g2
        rp[tid] = make_float4(sh, 0.25f * alpha * alpha, 0.25f * g2 * g2, 0.5f * gd);
    }
    for (int k = tid; k < NBINS; k += 256) {
        float st, ct;
        sincosf((float)k * 1.5339807878856412e-3f, &st, &ct); // h = pi*k/2048
        tab[k] = make_float2(st, 2.0f * st * ct);             // (sin h, sin theta)
    }
    __syncthreads();

    for (int j = 0; j < 4; ++j) {
        const int r   = wave * 4 + j;          // row within block
        const int row = blockIdx.x * RPB + r;
        const float4 P = rp[r];                // wave-uniform -> LDS broadcast
        const int koff = row & 1;
        unsigned int* __restrict__ orow = out + (size_t)row * NBINS;
        uint2* __restrict__ op = (uint2*)(orow + koff);   // 8B-aligned by parity
        if (lane == 0)
            orow[koff ? 0 : 1024] = 0x3F800000u;          // H = 1 exactly
        #pragma unroll
        for (int i = 0; i < 8; ++i) {
            const int k = koff + 2 * lane + (i << 7);
            const float2 t0 = tab[k];
            const float2 t1 = tab[k + 1];      // merges into one 16B LDS access
            float dp0 = (P.x - t0.x) * (P.x + t0.x);
            float dp1 = (P.x - t1.x) * (P.x + t1.x);
            float D20 = dp0 * dp0,  D21 = dp1 * dp1;
            float S20 = t0.y * t0.y, S21 = t1.y * t1.y;
            float i0 = __builtin_amdgcn_rcpf(fmaf(P.z, S20, D20));
            float i1 = __builtin_amdgcn_rcpf(fmaf(P.z, S21, D21));
            float re0 = fmaf(P.y, S20, D20) * i0;
            float re1 = fmaf(P.y, S21, D21) * i1;
            float im0 = P.w * t0.y * dp0 * i0;
            float im1 = P.w * t1.y * dp1 * i1;
            op[lane + (i << 6)] = make_uint2(pack_bf16(im0, re0),
                                             pack_bf16(im1, re1));
        }
    }
}

extern "C" void kernel_launch(void* const* d_in, const int* in_sizes, int n_in,
                              void* d_out, int out_size, void* d_ws, size_t ws_size,
                              hipStream_t stream) {
    const float* center = (const float*)d_in[0];
    const float* gain   = (const float*)d_in[1];
    const float* q      = (const float*)d_in[2];
    eq_kernel<<<NBLK, 256, 0, stream>>>(center, gain, q, (unsigned int*)d_out);
}